// Round 9
// baseline (82.726 us; speedup 1.0000x reference)
//
#include <hip/hip_runtime.h>
#include <math.h>

#define BATCH 32768

typedef float f32x4 __attribute__((ext_vector_type(4)));
typedef unsigned int u32x2 __attribute__((ext_vector_type(2)));
typedef unsigned int u32x4 __attribute__((ext_vector_type(4)));

__device__ __forceinline__ long mklong(unsigned a, unsigned b) {
    u32x2 t = {a, b};
    return __builtin_bit_cast(long, t);
}
// pack 4 fp32 -> dword of 4 fp8 e4m3 (bytes 0..3)
__device__ __forceinline__ unsigned pack_fp8x4(float a, float b, float c, float d) {
    int r = __builtin_amdgcn_cvt_pk_fp8_f32(a, b, 0, false);
    r = __builtin_amdgcn_cvt_pk_fp8_f32(c, d, r, true);
    return (unsigned)r;
}
__device__ __forceinline__ int lamf(int q, int j) { return 16 * (j >> 2) + 4 * q + (j & 3); }

// ---- Prefix: fp8 A-frags for split chains -------------------------------
// Blocks: 0..1 fwd single (t_mid[0], v=branch); 2..61 fwd pairs
// (i=(b-2)>>2, v=(b-2)&3: P = t_mid[2i+1][v&1] * t_mid[2i+2][v>>1], frag of
// P^T for row-vec chain); 62..63 bwd single (t_mid[61]); 64..123 bwd pairs
// (i: P = t_mid[59-2i][v&1] * t_mid[60-2i][v>>1], frag of P for col-vec).
// fp8 16x16x32 A-layout: lane l holds A[m=l&15][k=(l>>4)*8+j] in byte j;
// k relabeled by lam so the main loop's D->B handoff is in-lane.
__global__ __launch_bounds__(64) void prefix_kernel(const float* __restrict__ t_mid,
                                                    unsigned* __restrict__ wsP) {
    __shared__ float M1s[1024], M2s[1024];
    const int l = threadIdx.x, q = l >> 4, m = l & 15;
    const int bi = blockIdx.x;

    bool fwd, pair;
    int v, m1i = 0, m2i = 0;
    if (bi < 2)       { fwd = true;  pair = false; v = bi;            m1i = 0; }
    else if (bi < 62) { fwd = true;  pair = true;  v = (bi - 2) & 3;  int i = (bi - 2) >> 2;  m1i = 2 * i + 1; m2i = 2 * i + 2; }
    else if (bi < 64) { fwd = false; pair = false; v = bi - 62;       m1i = 61; }
    else              { fwd = false; pair = true;  v = (bi - 64) & 3; int i = (bi - 64) >> 2; m1i = 59 - 2 * i; m2i = 60 - 2 * i; }

    float o0[8], o1[8];
    if (pair) {
        const float4* s1 = (const float4*)(t_mid + (size_t)(m1i * 2 + (v & 1)) * 1024);
        const float4* s2 = (const float4*)(t_mid + (size_t)(m2i * 2 + (v >> 1)) * 1024);
        #pragma unroll
        for (int c = 0; c < 4; ++c) {
            ((float4*)M1s)[c * 64 + l] = s1[c * 64 + l];
            ((float4*)M2s)[c * 64 + l] = s2[c * 64 + l];
        }
        __syncthreads();
        if (fwd) {  // o_t[j] = sum_c M1[lam(q,j)][c] * M2[c][16t+m]
            float colv[2][32];
            #pragma unroll
            for (int t = 0; t < 2; ++t)
                #pragma unroll
                for (int c = 0; c < 32; ++c) colv[t][c] = M2s[c * 32 + 16 * t + m];
            #pragma unroll
            for (int j = 0; j < 8; ++j) {
                int a = lamf(q, j);
                float a0 = 0.f, a1 = 0.f;
                #pragma unroll
                for (int c = 0; c < 32; ++c) {
                    float r = M1s[a * 32 + c];
                    a0 = fmaf(r, colv[0][c], a0);
                    a1 = fmaf(r, colv[1][c], a1);
                }
                o0[j] = a0; o1[j] = a1;
            }
        } else {    // o_t[j] = sum_c M1[16t+m][c] * M2[c][lam(q,j)]
            float rowv[2][32];
            #pragma unroll
            for (int t = 0; t < 2; ++t)
                #pragma unroll
                for (int c = 0; c < 32; ++c) rowv[t][c] = M1s[(16 * t + m) * 32 + c];
            #pragma unroll
            for (int j = 0; j < 8; ++j) {
                int a = lamf(q, j);
                float a0 = 0.f, a1 = 0.f;
                #pragma unroll
                for (int c = 0; c < 32; ++c) {
                    float s = M2s[c * 32 + a];
                    a0 = fmaf(rowv[0][c], s, a0);
                    a1 = fmaf(rowv[1][c], s, a1);
                }
                o0[j] = a0; o1[j] = a1;
            }
        }
    } else {
        const float* T = t_mid + (size_t)(m1i * 2 + v) * 1024;
        #pragma unroll
        for (int j = 0; j < 8; ++j) {
            int a = lamf(q, j);
            if (fwd) { o0[j] = T[a * 32 + m];      o1[j] = T[a * 32 + 16 + m]; }
            else     { o0[j] = T[m * 32 + a];      o1[j] = T[(16 + m) * 32 + a]; }
        }
    }

    u32x4 outw;
    outw[0] = pack_fp8x4(o0[0], o0[1], o0[2], o0[3]);
    outw[1] = pack_fp8x4(o0[4], o0[5], o0[6], o0[7]);
    outw[2] = pack_fp8x4(o1[0], o1[1], o1[2], o1[3]);
    outw[3] = pack_fp8x4(o1[4], o1[5], o1[6], o1[7]);
    ((u32x4*)wsP)[bi * 64 + l] = outw;
}

// ---------------------------- Main MFMA kernel -----------------------------
// Block = 4 waves: wave 2g   = FORWARD  chain for elements [base+32g, +32)
//                  wave 2g+1 = BACKWARD chain for the same elements.
// Each wave: 32 elements = 2 fp8 B-frags sharing the A-frags; 1 single step
// + 15 pair steps (masked-B variant select, accumulating MFMAs), pow2
// rescale each step (exact log bookkeeping). One barrier at the end: fwd
// writes f to LDS, bwd computes amp = f.g -> log.
__global__ __launch_bounds__(256, 2) void mps_mfma_kernel(
    const float* __restrict__ t_first,
    const float* __restrict__ t_last,
    const int*   __restrict__ x,
    const unsigned* __restrict__ wsP,
    float* __restrict__ out)
{
    __shared__ float Lf[2][64][17];
    __shared__ int   Le[2][32];

    const int tid  = threadIdx.x;
    const int w    = tid >> 6;
    const int l    = tid & 63;
    const int q    = l >> 4;
    const int e    = l & 15;
    const bool isf = (w & 1) == 0;
    const int egrp = w >> 1;
    const int base = blockIdx.x * 64 + egrp * 32;

    auto build_mask = [&](int elem) -> unsigned long long {
        const int4* xr = (const int4*)(x + (size_t)elem * 64 + 16 * q);
        unsigned chunk = 0;
        #pragma unroll
        for (int c = 0; c < 4; ++c) {
            int4 vv = xr[c];
            chunk |= (unsigned)(vv.x > 0) << (4 * c + 0);
            chunk |= (unsigned)(vv.y > 0) << (4 * c + 1);
            chunk |= (unsigned)(vv.z > 0) << (4 * c + 2);
            chunk |= (unsigned)(vv.w > 0) << (4 * c + 3);
        }
        unsigned sh = chunk << ((q & 1) * 16);
        unsigned lo = (q < 2) ? sh : 0u;
        unsigned hi = (q >= 2) ? sh : 0u;
        lo |= (unsigned)__shfl_xor((int)lo, 16);
        lo |= (unsigned)__shfl_xor((int)lo, 32);
        hi |= (unsigned)__shfl_xor((int)hi, 16);
        hi |= (unsigned)__shfl_xor((int)hi, 32);
        return ((unsigned long long)hi << 32) | lo;
    };
    const unsigned long long mA = build_mask(base + e);
    const unsigned long long mB = build_mask(base + 16 + e);

    // ---- Init states in B-frag component order (slot (q,j) = comp lam). ----
    float stA[8], stB[8];
    {
        const float* pa;
        const float* pb;
        if (isf) {
            pa = t_first + ((mA & 1ull) ? 32 : 0);
            pb = t_first + ((mB & 1ull) ? 32 : 0);
        } else {
            pa = t_last + (((mA >> 63) & 1ull) ? 32 : 0);
            pb = t_last + (((mB >> 63) & 1ull) ? 32 : 0);
        }
        #pragma unroll
        for (int j = 0; j < 8; ++j) {
            int c = lamf(q, j);
            stA[j] = pa[c];
            stB[j] = pb[c];
        }
    }
    unsigned BdA0 = pack_fp8x4(stA[0], stA[1], stA[2], stA[3]);
    unsigned BdA1 = pack_fp8x4(stA[4], stA[5], stA[6], stA[7]);
    unsigned BdB0 = pack_fp8x4(stB[0], stB[1], stB[2], stB[3]);
    unsigned BdB1 = pack_fp8x4(stB[4], stB[5], stB[6], stB[7]);

    int expA = 0, expB = 0;
    const f32x4 cz = {0.f, 0.f, 0.f, 0.f};
    const u32x4* W = (const u32x4*)wsP + l + (isf ? 0 : 62 * 64);

    u32x4 Qs[2];
    Qs[0] = W[0]; Qs[1] = W[64];
    u32x4 Q[2][4];
    #pragma unroll
    for (int v = 0; v < 4; ++v) { Q[0][v] = W[(2 + v) * 64]; Q[1][v] = W[(6 + v) * 64]; }

    auto dostep = [&](u32x4* Qv, int nvar, unsigned vlA, unsigned vlB,
                      const u32x4* pf) {
        f32x4 yA0 = cz, yA1 = cz, yB0 = cz, yB1 = cz;
        #pragma unroll
        for (int v = 0; v < 4; ++v) {
            if (v >= nvar) break;
            long A0 = mklong(Qv[v][0], Qv[v][1]);
            long A1 = mklong(Qv[v][2], Qv[v][3]);
            bool sA = (vlA == (unsigned)v);
            bool sB = (vlB == (unsigned)v);
            long uA = mklong(sA ? BdA0 : 0u, sA ? BdA1 : 0u);
            long uB = mklong(sB ? BdB0 : 0u, sB ? BdB1 : 0u);
            yA0 = __builtin_amdgcn_mfma_f32_16x16x32_fp8_fp8(A0, uA, yA0, 0, 0, 0);
            yA1 = __builtin_amdgcn_mfma_f32_16x16x32_fp8_fp8(A1, uA, yA1, 0, 0, 0);
            yB0 = __builtin_amdgcn_mfma_f32_16x16x32_fp8_fp8(A0, uB, yB0, 0, 0, 0);
            yB1 = __builtin_amdgcn_mfma_f32_16x16x32_fp8_fp8(A1, uB, yB1, 0, 0, 0);
        }
        if (pf) {
            #pragma unroll
            for (int v = 0; v < 4; ++v) Qv[v] = pf[v * 64];
        }
        #pragma unroll
        for (int r = 0; r < 4; ++r) {
            stA[r] = yA0[r]; stA[4 + r] = yA1[r];
            stB[r] = yB0[r]; stB[4 + r] = yB1[r];
        }
        // per-element pow2 rescale (exact log bookkeeping)
        float mxA = stA[0], mxB = stB[0];
        #pragma unroll
        for (int j = 1; j < 8; ++j) { mxA = fmaxf(mxA, stA[j]); mxB = fmaxf(mxB, stB[j]); }
        mxA = fmaxf(mxA, __shfl_xor(mxA, 16)); mxA = fmaxf(mxA, __shfl_xor(mxA, 32));
        mxB = fmaxf(mxB, __shfl_xor(mxB, 16)); mxB = fmaxf(mxB, __shfl_xor(mxB, 32));
        int exA = (int)((__float_as_uint(mxA) >> 23) & 0xFF) - 127;
        int exB = (int)((__float_as_uint(mxB) >> 23) & 0xFF) - 127;
        float scA = __uint_as_float((unsigned)(127 - exA) << 23);
        float scB = __uint_as_float((unsigned)(127 - exB) << 23);
        #pragma unroll
        for (int j = 0; j < 8; ++j) { stA[j] *= scA; stB[j] *= scB; }
        expA += exA; expB += exB;
        BdA0 = pack_fp8x4(stA[0], stA[1], stA[2], stA[3]);
        BdA1 = pack_fp8x4(stA[4], stA[5], stA[6], stA[7]);
        BdB0 = pack_fp8x4(stB[0], stB[1], stB[2], stB[3]);
        BdB1 = pack_fp8x4(stB[4], stB[5], stB[6], stB[7]);
    };

    // single step: fwd consumes bit 1, bwd bit 62
    {
        int ss = isf ? 1 : 62;
        dostep(Qs, 2, (unsigned)((mA >> ss) & 1ull), (unsigned)((mB >> ss) & 1ull), nullptr);
    }
    // 15 pair steps: fwd bits (2+2k,3+2k); bwd bits (60-2k,61-2k)
    #pragma unroll
    for (int k = 0; k < 15; ++k) {
        int sh = isf ? (2 + 2 * k) : (60 - 2 * k);
        unsigned vA = (unsigned)((mA >> sh) & 3ull);
        unsigned vB = (unsigned)((mB >> sh) & 3ull);
        const u32x4* pf = (k < 13) ? (W + (size_t)(2 + 4 * (k + 2)) * 64) : nullptr;
        dostep(Q[k & 1], 4, vA, vB, pf);
    }

    // ---- Combine: fwd publishes f; bwd computes amp = f.g -> log. ----
    if (isf) {
        #pragma unroll
        for (int j = 0; j < 8; ++j) {
            Lf[egrp][l][j]     = stA[j];
            Lf[egrp][l][8 + j] = stB[j];
        }
        if (q == 0) { Le[egrp][e] = expA; Le[egrp][16 + e] = expB; }
    }
    __syncthreads();
    if (!isf) {
        float ampA = 0.f, ampB = 0.f;
        #pragma unroll
        for (int j = 0; j < 8; ++j) {
            ampA = fmaf(Lf[egrp][l][j],     stA[j], ampA);
            ampB = fmaf(Lf[egrp][l][8 + j], stB[j], ampB);
        }
        ampA += __shfl_xor(ampA, 16); ampA += __shfl_xor(ampA, 32);
        ampB += __shfl_xor(ampB, 16); ampB += __shfl_xor(ampB, 32);
        if (l < 16) {
            out[base + l]      = logf(ampA) + 0.69314718055994531f * (float)(Le[egrp][l] + expA);
            out[base + 16 + l] = logf(ampB) + 0.69314718055994531f * (float)(Le[egrp][16 + l] + expB);
        }
    }
}

extern "C" void kernel_launch(void* const* d_in, const int* in_sizes, int n_in,
                              void* d_out, int out_size, void* d_ws, size_t ws_size,
                              hipStream_t stream) {
    const float* t_first = (const float*)d_in[0];
    const float* t_mid   = (const float*)d_in[1];
    const float* t_last  = (const float*)d_in[2];
    const int*   x       = (const int*)d_in[3];
    float* out           = (float*)d_out;

    unsigned* wsP = (unsigned*)d_ws;  // 124 frag blocks x 1 KB = 124 KB

    hipLaunchKernelGGL(prefix_kernel, dim3(124), dim3(64), 0, stream, t_mid, wsP);
    hipLaunchKernelGGL(mps_mfma_kernel, dim3(BATCH / 64), dim3(256), 0, stream,
                       t_first, t_last, x, wsP, out);
}

// Round 11
// 78.771 us; speedup vs baseline: 1.0502x; 1.0502x over previous
//
#include <hip/hip_runtime.h>
#include <math.h>

#define N_MID 62
#define NPAIR 31
#define BATCH 32768

typedef float f32x4 __attribute__((ext_vector_type(4)));
typedef unsigned int u32x2 __attribute__((ext_vector_type(2)));
typedef unsigned int u32x4 __attribute__((ext_vector_type(4)));

__device__ __forceinline__ long mklong(unsigned a, unsigned b) {
    u32x2 t = {a, b};
    return __builtin_bit_cast(long, t);
}
// pack 4 fp32 -> dword of 4 fp8 e4m3 (bytes 0..3 = a,b,c,d)
__device__ __forceinline__ unsigned pack_fp8x4(float a, float b, float c, float d) {
    int r = __builtin_amdgcn_cvt_pk_fp8_f32(a, b, 0, false);
    r = __builtin_amdgcn_cvt_pk_fp8_f32(c, d, r, true);
    return (unsigned)r;
}

// ---- Prefix: site-pair products T[2i][v0]*T[2i+1][v1] as fp8 A-frags ------
// Block = (pair i)*4 + variant v (v0=v&1 site 2i, v1=v>>1 site 2i+1).
// MFMA fp8 16x16x32 A-layout: lane l holds A[m=l&15][k=(l>>4)*8+j] in byte j.
// We store A_t[m,k] = P[lam(k)][16t+m], lam(8q+j)=16*(j>>2)+4q+(j&3), so the
// main loop's D->B handoff is purely in-lane (slot j=4t+r <- y_t[r]).
__global__ __launch_bounds__(64) void prefix_kernel(const float* __restrict__ t_mid,
                                                    unsigned* __restrict__ wsP) {
    __shared__ float M1s[1024], M2s[1024];
    const int l = threadIdx.x, q = l >> 4, m = l & 15;
    const int i = blockIdx.x >> 2, v = blockIdx.x & 3;

    const float4* s1 = (const float4*)(t_mid + (size_t)((2 * i) * 2 + (v & 1)) * 1024);
    const float4* s2 = (const float4*)(t_mid + (size_t)((2 * i + 1) * 2 + (v >> 1)) * 1024);
    #pragma unroll
    for (int c = 0; c < 4; ++c) {
        ((float4*)M1s)[c * 64 + l] = s1[c * 64 + l];
        ((float4*)M2s)[c * 64 + l] = s2[c * 64 + l];
    }
    __syncthreads();

    float colv[2][32];
    #pragma unroll
    for (int t = 0; t < 2; ++t)
        #pragma unroll
        for (int mm = 0; mm < 32; ++mm)
            colv[t][mm] = M2s[mm * 32 + 16 * t + m];

    float o0[8], o1[8];
    #pragma unroll
    for (int j = 0; j < 8; ++j) {
        int a = 16 * (j >> 2) + 4 * q + (j & 3);  // lam(8q+j)
        float acc0 = 0.f, acc1 = 0.f;
        #pragma unroll
        for (int mm = 0; mm < 32; ++mm) {
            float r = M1s[a * 32 + mm];
            acc0 = fmaf(r, colv[0][mm], acc0);
            acc1 = fmaf(r, colv[1][mm], acc1);
        }
        o0[j] = acc0;
        o1[j] = acc1;
    }

    u32x4 outw;
    outw[0] = pack_fp8x4(o0[0], o0[1], o0[2], o0[3]);
    outw[1] = pack_fp8x4(o0[4], o0[5], o0[6], o0[7]);
    outw[2] = pack_fp8x4(o1[0], o1[1], o1[2], o1[3]);
    outw[3] = pack_fp8x4(o1[4], o1[5], o1[6], o1[7]);
    ((u32x4*)wsP)[blockIdx.x * 64 + l] = outw;
}

// ---------------------------- Main MFMA kernel -----------------------------
// One wave = 16 batch elements (element = lane&15), no LDS, no barriers.
// State = fp8 B-frag (2 dwords): byte j of lane (q,e) holds component
// lam(8q+j) of element e. Per pair-step: 4 per-element-masked B copies
// (variant = 2 spin bits), 8 accumulating fp8 MFMAs split into two 2-deep
// chains per tile + v_add (halved dependency latency); pow2 rescale EVERY
// step (mandatory: fp8 e4m3 pack NaNs above 448 — r10 post-mortem), exact
// log bookkeeping; repack to fp8.
__global__ __launch_bounds__(256, 2) void mps_mfma_kernel(
    const float* __restrict__ t_first,
    const float* __restrict__ t_last,
    const int*   __restrict__ x,
    const unsigned* __restrict__ wsP,
    float* __restrict__ out)
{
    const int tid  = threadIdx.x;
    const int w    = tid >> 6;
    const int l    = tid & 63;
    const int q    = l >> 4;
    const int e    = l & 15;
    const int base = (blockIdx.x * 4 + w) * 16;

    // ---- Inline spin mask for element e: bit s = (x[base+e][s] > 0). ----
    unsigned long long mask;
    {
        const int4* xr = (const int4*)(x + (size_t)(base + e) * 64 + 16 * q);
        unsigned chunk = 0;
        #pragma unroll
        for (int c = 0; c < 4; ++c) {
            int4 vv = xr[c];
            chunk |= (unsigned)(vv.x > 0) << (4 * c + 0);
            chunk |= (unsigned)(vv.y > 0) << (4 * c + 1);
            chunk |= (unsigned)(vv.z > 0) << (4 * c + 2);
            chunk |= (unsigned)(vv.w > 0) << (4 * c + 3);
        }
        unsigned sh = chunk << ((q & 1) * 16);
        unsigned lo = (q < 2) ? sh : 0u;
        unsigned hi = (q >= 2) ? sh : 0u;
        lo |= (unsigned)__shfl_xor((int)lo, 16);
        lo |= (unsigned)__shfl_xor((int)lo, 32);
        hi |= (unsigned)__shfl_xor((int)hi, 16);
        hi |= (unsigned)__shfl_xor((int)hi, 32);
        mask = ((unsigned long long)hi << 32) | lo;
    }

    // ---- Init state (B-frag component order) from t_first[bit0]. ----
    float st[8];
    {
        const float* tf = t_first + ((mask & 1ull) ? 32 : 0);
        #pragma unroll
        for (int j = 0; j < 8; ++j)
            st[j] = tf[16 * (j >> 2) + 4 * q + (j & 3)];
    }
    unsigned long long mrot = mask >> 1;  // pairs consume bits 1..62; bit63 = t_last
    unsigned Bd0 = pack_fp8x4(st[0], st[1], st[2], st[3]);
    unsigned Bd1 = pack_fp8x4(st[4], st[5], st[6], st[7]);

    int expsum = 0;
    const f32x4 cz = {0.f, 0.f, 0.f, 0.f};

    // 2-step rolling prefetch of pair-frags: 4 variants x 16 B/lane per step.
    const u32x4* W = (const u32x4*)wsP + l;  // step i, variant v: + (i*4+v)*64
    u32x4 Q0[4], Q1[4];
    #pragma unroll
    for (int v = 0; v < 4; ++v) Q0[v] = W[v * 64];
    #pragma unroll
    for (int v = 0; v < 4; ++v) Q1[v] = W[(4 + v) * 64];

    auto step = [&](u32x4* Q, const u32x4* pf) {
        unsigned vl = (unsigned)mrot & 3u;
        mrot >>= 2;

        // Split accumulation: two 2-deep chains per tile, then add.
        f32x4 p0 = cz, p1 = cz, r0 = cz, r1 = cz;
        {
            bool s0 = (vl == 0u), s1 = (vl == 1u), s2 = (vl == 2u), s3 = (vl == 3u);
            long u0 = mklong(s0 ? Bd0 : 0u, s0 ? Bd1 : 0u);
            long u1 = mklong(s1 ? Bd0 : 0u, s1 ? Bd1 : 0u);
            long u2 = mklong(s2 ? Bd0 : 0u, s2 ? Bd1 : 0u);
            long u3 = mklong(s3 ? Bd0 : 0u, s3 ? Bd1 : 0u);
            p0 = __builtin_amdgcn_mfma_f32_16x16x32_fp8_fp8(mklong(Q[0][0], Q[0][1]), u0, p0, 0, 0, 0);
            p1 = __builtin_amdgcn_mfma_f32_16x16x32_fp8_fp8(mklong(Q[0][2], Q[0][3]), u0, p1, 0, 0, 0);
            r0 = __builtin_amdgcn_mfma_f32_16x16x32_fp8_fp8(mklong(Q[2][0], Q[2][1]), u2, r0, 0, 0, 0);
            r1 = __builtin_amdgcn_mfma_f32_16x16x32_fp8_fp8(mklong(Q[2][2], Q[2][3]), u2, r1, 0, 0, 0);
            p0 = __builtin_amdgcn_mfma_f32_16x16x32_fp8_fp8(mklong(Q[1][0], Q[1][1]), u1, p0, 0, 0, 0);
            p1 = __builtin_amdgcn_mfma_f32_16x16x32_fp8_fp8(mklong(Q[1][2], Q[1][3]), u1, p1, 0, 0, 0);
            r0 = __builtin_amdgcn_mfma_f32_16x16x32_fp8_fp8(mklong(Q[3][0], Q[3][1]), u3, r0, 0, 0, 0);
            r1 = __builtin_amdgcn_mfma_f32_16x16x32_fp8_fp8(mklong(Q[3][2], Q[3][3]), u3, r1, 0, 0, 0);
        }

        if (pf) {
            #pragma unroll
            for (int v = 0; v < 4; ++v) Q[v] = pf[v * 64];
        }

        #pragma unroll
        for (int r = 0; r < 4; ++r) {
            st[r]     = p0[r] + r0[r];
            st[4 + r] = p1[r] + r1[r];
        }

        // per-element pow2 rescale (MANDATORY every step: fp8 pack NaNs >448)
        float mx = st[0];
        #pragma unroll
        for (int j = 1; j < 8; ++j) mx = fmaxf(mx, st[j]);
        mx = fmaxf(mx, __shfl_xor(mx, 16));
        mx = fmaxf(mx, __shfl_xor(mx, 32));
        int ex = (int)((__float_as_uint(mx) >> 23) & 0xFF) - 127;
        float sc = __uint_as_float((unsigned)(127 - ex) << 23);
        #pragma unroll
        for (int j = 0; j < 8; ++j) st[j] *= sc;
        expsum += ex;

        Bd0 = pack_fp8x4(st[0], st[1], st[2], st[3]);
        Bd1 = pack_fp8x4(st[4], st[5], st[6], st[7]);
    };

    const u32x4* pf = W + 8 * 64;  // step-2 frags
    for (int k = 0; k < 15; ++k) {
        step(Q0, pf);                               // step 2k
        step(Q1, (k < 14) ? pf + 4 * 64 : nullptr); // step 2k+1
        pf += 8 * 64;
    }
    step(Q0, nullptr);  // step 30

    // ---- Epilogue: amp = dot(state, t_last[bit63]); reduce over q. ----
    const float* tl = t_last + ((mrot & 1ull) ? 32 : 0);
    float amp = 0.f;
    #pragma unroll
    for (int j = 0; j < 8; ++j)
        amp = fmaf(st[j], tl[16 * (j >> 2) + 4 * q + (j & 3)], amp);
    amp += __shfl_xor(amp, 16);
    amp += __shfl_xor(amp, 32);

    if (l < 16)
        out[base + l] = logf(amp) + 0.69314718055994531f * (float)expsum;
}

extern "C" void kernel_launch(void* const* d_in, const int* in_sizes, int n_in,
                              void* d_out, int out_size, void* d_ws, size_t ws_size,
                              hipStream_t stream) {
    const float* t_first = (const float*)d_in[0];
    const float* t_mid   = (const float*)d_in[1];
    const float* t_last  = (const float*)d_in[2];
    const int*   x       = (const int*)d_in[3];
    float* out           = (float*)d_out;

    unsigned* wsP = (unsigned*)d_ws;  // 31 pairs x 4 variants x 1 KB = 124 KB

    hipLaunchKernelGGL(prefix_kernel, dim3(NPAIR * 4), dim3(64), 0, stream, t_mid, wsP);
    hipLaunchKernelGGL(mps_mfma_kernel, dim3(BATCH / 64), dim3(256), 0, stream,
                       t_first, t_last, x, wsP, out);
}